// Round 8
// baseline (258.965 us; speedup 1.0000x reference)
//
#include <hip/hip_runtime.h>
#include <stdint.h>

typedef unsigned long long u64;

#define BATCH 16384
#define FEAT  1024
#define KW    16          // 1024 bits / 64 per row
#define NCLS  10

// ---- workspace layout (bytes) ----
// XA/XB: column-major packed strips, u64 [KW][BATCH] = 2 MB each
#define OFF_XA   ((size_t)0)
#define OFF_XB   ((size_t)(2u * 1024u * 1024u))
#define OFF_WP1  ((size_t)(4u * 1024u * 1024u))          // 128 KB each, row-major
#define OFF_WP2  (OFF_WP1 + (size_t)FEAT * KW * 8)
#define OFF_WP3  (OFF_WP2 + (size_t)FEAT * KW * 8)
#define OFF_WP4  (OFF_WP3 + (size_t)FEAT * KW * 8)       // 160 u64
#define OFF_TH   (OFF_WP4 + (size_t)2048)                 // 3*1024 int2

// ---------------------------------------------------------------------------
// Fused prep, float4 + shuffle-combine packing (4 elems/thread).
#define NB_X   16384           // 16384*1024 / (256*4)
#define NB_W   1024            // 1024*1024 / (256*4)
#define NB_W4  10              // 10*1024  / (256*4)
#define NB_TH  12              // 3*1024/256

__global__ void __launch_bounds__(256) prep_kernel(
    const float* __restrict__ x,
    const float* __restrict__ W1, const float* __restrict__ W2,
    const float* __restrict__ W3, const float* __restrict__ W4,
    const float* __restrict__ g1, const float* __restrict__ b1,
    const float* __restrict__ m1, const float* __restrict__ v1,
    const float* __restrict__ g2, const float* __restrict__ b2,
    const float* __restrict__ m2, const float* __restrict__ v2,
    const float* __restrict__ g3, const float* __restrict__ b3,
    const float* __restrict__ m3, const float* __restrict__ v3,
    u64* __restrict__ XA, u64* __restrict__ Wp1, u64* __restrict__ Wp2,
    u64* __restrict__ Wp3, u64* __restrict__ Wp4, int2* __restrict__ TH)
{
    int b = blockIdx.x;
    if (b >= NB_X + 3 * NB_W + NB_W4) {
        int gid = (b - (NB_X + 3 * NB_W + NB_W4)) * 256 + threadIdx.x; // 0..3071
        int l = gid >> 10, j = gid & 1023;
        const float *g, *bb, *m, *v;
        if (l == 0)      { g = g1; bb = b1; m = m1; v = v1; }
        else if (l == 1) { g = g2; bb = b2; m = m2; v = v2; }
        else             { g = g3; bb = b3; m = m3; v = v3; }
        double gd = (double)g[j], bd = (double)bb[j], md = (double)m[j], vd = (double)v[j];
        double s = gd / sqrt(vd + 1e-5);
        int ti, flip;
        if (s > 0.0)      { ti = (int)ceil(md - bd / s);  flip = 0; }
        else if (s < 0.0) { ti = (int)floor(md - bd / s); flip = 1; }
        else              { ti = (bd >= 0.0) ? -2000000 : 2000000; flip = 0; }
        TH[gid] = make_int2(ti, flip);
        return;
    }
    const float* src; u64* dst; float thr; int base; int isX = 0;
    if (b < NB_X)                    { src = x;  dst = XA;  thr = 0.5f; base = b; isX = 1; }
    else if (b < NB_X + NB_W)        { src = W1; dst = Wp1; thr = 0.0f; base = b - NB_X; }
    else if (b < NB_X + 2 * NB_W)    { src = W2; dst = Wp2; thr = 0.0f; base = b - (NB_X + NB_W); }
    else if (b < NB_X + 3 * NB_W)    { src = W3; dst = Wp3; thr = 0.0f; base = b - (NB_X + 2 * NB_W); }
    else                             { src = W4; dst = Wp4; thr = 0.0f; base = b - (NB_X + 3 * NB_W); }

    int e0 = base * 1024 + threadIdx.x * 4;
    float4 xv = *(const float4*)(src + e0);
    unsigned int nib = (xv.x >= thr ? 1u : 0u) | (xv.y >= thr ? 2u : 0u)
                     | (xv.z >= thr ? 4u : 0u) | (xv.w >= thr ? 8u : 0u);
    unsigned int b8  = nib | (__shfl_xor(nib, 1) << 4);
    unsigned int b16 = b8  | (__shfl_xor(b8, 2) << 8);
    unsigned int b32 = b16 | (__shfl_xor(b16, 4) << 16);
    u64 word = (u64)b32 | ((u64)__shfl_xor(b32, 8) << 32);
    int lane = threadIdx.x & 63;
    if ((lane & 15) == 0) {
        int g = e0 >> 6;
        if (isX) { int row = g >> 4, wq = g & 15; XA[(size_t)wq * BATCH + row] = word; }
        else dst[g] = word;
    }
}

// ---------------------------------------------------------------------------
// XNOR-MAC of one uint4 of X against one uint4 of W (scalar), accumulating.
// Pinned with inline asm: acc stays "+v", W stays "s", exactly 8 VALU insts.
#define MACQ(acc, xv, wv)                                                   \
    { unsigned int t_;                                                      \
      asm("v_xor_b32 %0, %6, %2\n\t"                                       \
          "v_bcnt_u32_b32 %1, %0, %1\n\t"                                  \
          "v_xor_b32 %0, %7, %3\n\t"                                       \
          "v_bcnt_u32_b32 %1, %0, %1\n\t"                                  \
          "v_xor_b32 %0, %8, %4\n\t"                                       \
          "v_bcnt_u32_b32 %1, %0, %1\n\t"                                  \
          "v_xor_b32 %0, %9, %5\n\t"                                       \
          "v_bcnt_u32_b32 %1, %0, %1"                                      \
          : "=&v"(t_), "+v"(acc)                                            \
          : "v"((xv).x), "v"((xv).y), "v"((xv).z), "v"((xv).w),             \
            "s"((wv).x), "s"((wv).y), "s"((wv).z), "s"((wv).w)); }

// ---------------------------------------------------------------------------
// Binary GEMM layer. 256 rows x 128 cols per 256-thread block (512 blocks).
// Thread = rows {lane, lane+64, lane+128, lane+192}; wave = 32 cols (uniform).
// X in LDS, unpadded pitch 16 u64, XOR-swizzled at uint4 granularity:
//   uint4 slot' = slot ^ (row & 7)  -> 8-row groups cover all 32 banks,
//   16 B alignment preserved for ds_read_b128. All 4 of a lane's rows share
//   swizzle constant (lane & 7) since they differ by multiples of 64.
// W + thresholds via wave-uniform scalar loads; MAC pinned with asm (R7).
// 4 rows/thread doubles VALU per wave vs R7, halving the relative cost of
// the s_load latency the SGPR file can't prefetch past (R8 theory).
__global__ void __launch_bounds__(256)
gemm_bin_kernel(const u64* __restrict__ Xin, const u64* __restrict__ Wp,
                const int2* __restrict__ th, u64* __restrict__ Xout) {
    __shared__ u64 Xs[256][KW];      // 32 KB, swizzled storage

    const int tid = threadIdx.x;
    const int bc = blockIdx.x & 7;    // col block (8 x 128 cols)
    const int br = blockIdx.x >> 3;   // row block (64 x 256 rows)
    const int r0 = br * 256;

    // stage X: 4096 u64; for fixed k: wq=k, row=tid -> fully coalesced
#pragma unroll
    for (int k = 0; k < 16; ++k) {
        int f = tid + k * 256;
        int row = f & 255;
        int wq = f >> 8;
        int slot = (((wq >> 1) ^ (row & 7)) << 1) | (wq & 1);
        Xs[row][slot] = Xin[(size_t)wq * BATCH + r0 + row];
    }
    __syncthreads();

    const int lane = tid & 63;
    const int w = __builtin_amdgcn_readfirstlane(tid >> 6);   // wave id, SGPR
    const int cbase = bc * 128 + w * 32;                      // scalar
    const int c = lane & 7;                                   // swizzle const

    const uint4* xr0 = (const uint4*)&Xs[lane][0];
    const uint4* xr1 = (const uint4*)&Xs[lane + 64][0];
    const uint4* xr2 = (const uint4*)&Xs[lane + 128][0];
    const uint4* xr3 = (const uint4*)&Xs[lane + 192][0];

    unsigned int bits0 = 0, bits1 = 0, bits2 = 0, bits3 = 0;

#pragma unroll 1
    for (int jc = 0; jc < 4; ++jc) {
        int acc0[8], acc1[8], acc2[8], acc3[8];
#pragma unroll
        for (int u = 0; u < 8; ++u) { acc0[u] = 0; acc1[u] = 0; acc2[u] = 0; acc3[u] = 0; }

#pragma unroll
        for (int sp = 0; sp < 8; ++sp) {          // uint4 slots (2 u64 each)
            uint4 xa = xr0[sp ^ c];
            uint4 xb = xr1[sp ^ c];
            uint4 xc = xr2[sp ^ c];
            uint4 xd = xr3[sp ^ c];
#pragma unroll
            for (int u = 0; u < 8; ++u) {
                const uint4* wrow = (const uint4*)(Wp + (size_t)(cbase + jc * 8 + u) * KW);
                uint4 wv = wrow[sp];               // scalar load (uniform addr)
                MACQ(acc0[u], xa, wv);
                MACQ(acc1[u], xb, wv);
                MACQ(acc2[u], xc, wv);
                MACQ(acc3[u], xd, wv);
            }
        }
#pragma unroll
        for (int u = 0; u < 8; ++u) {
            int2 t = th[cbase + jc * 8 + u];
            int h0 = 1024 - 2 * acc0[u];
            int h1 = 1024 - 2 * acc1[u];
            int h2 = 1024 - 2 * acc2[u];
            int h3 = 1024 - 2 * acc3[u];
            unsigned int s = (unsigned int)(jc * 8 + u);
            bits0 |= (unsigned int)(t.y ? (h0 <= t.x) : (h0 >= t.x)) << s;
            bits1 |= (unsigned int)(t.y ? (h1 <= t.x) : (h1 >= t.x)) << s;
            bits2 |= (unsigned int)(t.y ? (h2 <= t.x) : (h2 >= t.x)) << s;
            bits3 |= (unsigned int)(t.y ? (h3 <= t.x) : (h3 >= t.x)) << s;
        }
    }

    // store: output strips as u32 halves; wq = cbase>>6, half = (cbase>>5)&1
    const int wq = cbase >> 6;
    const int half = (cbase >> 5) & 1;
    unsigned int* out32 = (unsigned int*)Xout;
    size_t ob = (size_t)wq * 2 * BATCH;
    out32[ob + (r0 + lane) * 2 + half]       = bits0;
    out32[ob + (r0 + lane + 64) * 2 + half]  = bits1;
    out32[ob + (r0 + lane + 128) * 2 + half] = bits2;
    out32[ob + (r0 + lane + 192) * 2 + half] = bits3;
}

// ---------------------------------------------------------------------------
// Final 1024 -> 10 binary matmul + TensorNorm. X3 column-major strips.
__global__ void __launch_bounds__(256) final_layer_kernel(
    const u64* __restrict__ X3, const u64* __restrict__ W4p,
    const float* __restrict__ tw, const float* __restrict__ tb,
    const float* __restrict__ tm, const float* __restrict__ tv,
    float* __restrict__ out) {
    __shared__ u64 Wl[NCLS * KW];
    if (threadIdx.x < NCLS * KW) Wl[threadIdx.x] = W4p[threadIdx.x];
    __syncthreads();

    int row = blockIdx.x * 256 + threadIdx.x;
    u64 xr[KW];
#pragma unroll
    for (int wq = 0; wq < KW; ++wq) xr[wq] = X3[(size_t)wq * BATCH + row];

    double sc = (double)tw[0] / sqrt((double)tv[0] + 1e-4);
    double off = (double)tb[0] - (double)tm[0] * sc;

#pragma unroll
    for (int cc = 0; cc < NCLS; ++cc) {
        int p = 0;
#pragma unroll
        for (int wq = 0; wq < KW; ++wq)
            p += __builtin_popcountll(xr[wq] ^ Wl[cc * KW + wq]);
        int h = 1024 - 2 * p;
        out[(size_t)row * NCLS + cc] = (float)((double)h * sc + off);
    }
}

// ---------------------------------------------------------------------------
extern "C" void kernel_launch(void* const* d_in, const int* in_sizes, int n_in,
                              void* d_out, int out_size, void* d_ws, size_t ws_size,
                              hipStream_t stream) {
    const float* x  = (const float*)d_in[0];
    const float* W1 = (const float*)d_in[1];
    const float* W2 = (const float*)d_in[2];
    const float* W3 = (const float*)d_in[3];
    const float* W4 = (const float*)d_in[4];
    const float* g1 = (const float*)d_in[5];
    const float* b1 = (const float*)d_in[6];
    const float* m1 = (const float*)d_in[7];
    const float* v1 = (const float*)d_in[8];
    const float* g2 = (const float*)d_in[9];
    const float* b2 = (const float*)d_in[10];
    const float* m2 = (const float*)d_in[11];
    const float* v2 = (const float*)d_in[12];
    const float* g3 = (const float*)d_in[13];
    const float* b3 = (const float*)d_in[14];
    const float* m3 = (const float*)d_in[15];
    const float* v3 = (const float*)d_in[16];
    const float* tw = (const float*)d_in[17];
    const float* tb = (const float*)d_in[18];
    const float* tm = (const float*)d_in[19];
    const float* tv = (const float*)d_in[20];

    char* ws = (char*)d_ws;
    u64* XA  = (u64*)(ws + OFF_XA);
    u64* XB  = (u64*)(ws + OFF_XB);
    u64* Wp1 = (u64*)(ws + OFF_WP1);
    u64* Wp2 = (u64*)(ws + OFF_WP2);
    u64* Wp3 = (u64*)(ws + OFF_WP3);
    u64* Wp4 = (u64*)(ws + OFF_WP4);
    int2* TH = (int2*)(ws + OFF_TH);

    int nprep = NB_X + 3 * NB_W + NB_W4 + NB_TH;
    prep_kernel<<<nprep, 256, 0, stream>>>(x, W1, W2, W3, W4,
                                           g1, b1, m1, v1, g2, b2, m2, v2,
                                           g3, b3, m3, v3,
                                           XA, Wp1, Wp2, Wp3, Wp4, TH);

    gemm_bin_kernel<<<512, 256, 0, stream>>>(XA, Wp1, TH,        XB);
    gemm_bin_kernel<<<512, 256, 0, stream>>>(XB, Wp2, TH + 1024, XA);
    gemm_bin_kernel<<<512, 256, 0, stream>>>(XA, Wp3, TH + 2048, XB);

    final_layer_kernel<<<64, 256, 0, stream>>>(XB, Wp4, tw, tb, tm, tv,
                                               (float*)d_out);
}

// Round 11
// 257.788 us; speedup vs baseline: 1.0046x; 1.0046x over previous
//
#include <hip/hip_runtime.h>
#include <stdint.h>

typedef unsigned long long u64;

#define BATCH 16384
#define FEAT  1024
#define KW    16          // 1024 bits / 64 per row
#define NCLS  10

// ---- workspace layout (bytes) ----
// XA/XB: column-major packed strips, u64 [KW][BATCH] = 2 MB each
#define OFF_XA   ((size_t)0)
#define OFF_XB   ((size_t)(2u * 1024u * 1024u))
#define OFF_WP1  ((size_t)(4u * 1024u * 1024u))          // 128 KB each, row-major
#define OFF_WP2  (OFF_WP1 + (size_t)FEAT * KW * 8)
#define OFF_WP3  (OFF_WP2 + (size_t)FEAT * KW * 8)
#define OFF_WP4  (OFF_WP3 + (size_t)FEAT * KW * 8)       // 160 u64
#define OFF_TH   (OFF_WP4 + (size_t)2048)                 // 3*1024 int2

// ---------------------------------------------------------------------------
// Fused prep, float4 + shuffle-combine packing (4 elems/thread).
#define NB_X   16384           // 16384*1024 / (256*4)
#define NB_W   1024            // 1024*1024 / (256*4)
#define NB_W4  10              // 10*1024  / (256*4)
#define NB_TH  12              // 3*1024/256
#define NB_PACK (NB_X + 3 * NB_W + NB_W4)

__global__ void __launch_bounds__(256) prep_kernel(
    const float* __restrict__ x,
    const float* __restrict__ W1, const float* __restrict__ W2,
    const float* __restrict__ W3, const float* __restrict__ W4,
    const float* __restrict__ g1, const float* __restrict__ b1,
    const float* __restrict__ m1, const float* __restrict__ v1,
    const float* __restrict__ g2, const float* __restrict__ b2,
    const float* __restrict__ m2, const float* __restrict__ v2,
    const float* __restrict__ g3, const float* __restrict__ b3,
    const float* __restrict__ m3, const float* __restrict__ v3,
    u64* __restrict__ XA, u64* __restrict__ Wp1, u64* __restrict__ Wp2,
    u64* __restrict__ Wp3, u64* __restrict__ Wp4, int2* __restrict__ TH)
{
    int b = blockIdx.x;
    if (b >= NB_PACK) {
        int gid = (b - NB_PACK) * 256 + threadIdx.x;   // 0..3071
        int l = gid >> 10, j = gid & 1023;
        const float *g, *bb, *m, *v;
        if (l == 0)      { g = g1; bb = b1; m = m1; v = v1; }
        else if (l == 1) { g = g2; bb = b2; m = m2; v = v2; }
        else             { g = g3; bb = b3; m = m3; v = v3; }
        double gd = (double)g[j], bd = (double)bb[j], md = (double)m[j], vd = (double)v[j];
        double s = gd / sqrt(vd + 1e-5);
        int ti, flip;
        if (s > 0.0)      { ti = (int)ceil(md - bd / s);  flip = 0; }
        else if (s < 0.0) { ti = (int)floor(md - bd / s); flip = 1; }
        else              { ti = (bd >= 0.0) ? -2000000 : 2000000; flip = 0; }
        TH[gid] = make_int2(ti, flip);
        return;
    }
    const float* src; u64* dst; float thr; int base; int isX = 0;
    if (b < NB_X)                    { src = x;  dst = XA;  thr = 0.5f; base = b; isX = 1; }
    else if (b < NB_X + NB_W)        { src = W1; dst = Wp1; thr = 0.0f; base = b - NB_X; }
    else if (b < NB_X + 2 * NB_W)    { src = W2; dst = Wp2; thr = 0.0f; base = b - (NB_X + NB_W); }
    else if (b < NB_X + 3 * NB_W)    { src = W3; dst = Wp3; thr = 0.0f; base = b - (NB_X + 2 * NB_W); }
    else                             { src = W4; dst = Wp4; thr = 0.0f; base = b - (NB_X + 3 * NB_W); }

    int e0 = base * 1024 + threadIdx.x * 4;
    float4 xv = *(const float4*)(src + e0);
    unsigned int nib = (xv.x >= thr ? 1u : 0u) | (xv.y >= thr ? 2u : 0u)
                     | (xv.z >= thr ? 4u : 0u) | (xv.w >= thr ? 8u : 0u);
    unsigned int b8  = nib | (__shfl_xor(nib, 1) << 4);
    unsigned int b16 = b8  | (__shfl_xor(b8, 2) << 8);
    unsigned int b32 = b16 | (__shfl_xor(b16, 4) << 16);
    u64 word = (u64)b32 | ((u64)__shfl_xor(b32, 8) << 32);
    int lane = threadIdx.x & 63;
    if ((lane & 15) == 0) {
        int g = e0 >> 6;
        if (isX) { int row = g >> 4, wq = g & 15; XA[(size_t)wq * BATCH + row] = word; }
        else dst[g] = word;
    }
}

// ---------------------------------------------------------------------------
// Dual-row XNOR-MAC: two X uint4s (two rows) against ONE scalar W uint4.
// Interleaved so every v_bcnt issues 2 insts (4 cyc) after the v_xor that
// feeds it -> no VALU forwarding bubble even at 1 wave/SIMD (R8 post-mortem:
// single-row chain issued at ~4 cyc/inst-pair, exactly 2x the floor).
// acc self-dependencies are 8 cyc apart. Exactly 16 VALU insts; accs pinned
// "+v", W pinned "s".
#define MACQ2(accA, accB, xa, xb, wv)                                       \
    { unsigned int t0_, t1_;                                                \
      asm("v_xor_b32 %0, %12, %4\n\t"                                       \
          "v_xor_b32 %1, %12, %8\n\t"                                       \
          "v_bcnt_u32_b32 %2, %0, %2\n\t"                                   \
          "v_bcnt_u32_b32 %3, %1, %3\n\t"                                   \
          "v_xor_b32 %0, %13, %5\n\t"                                       \
          "v_xor_b32 %1, %13, %9\n\t"                                       \
          "v_bcnt_u32_b32 %2, %0, %2\n\t"                                   \
          "v_bcnt_u32_b32 %3, %1, %3\n\t"                                   \
          "v_xor_b32 %0, %14, %6\n\t"                                       \
          "v_xor_b32 %1, %14, %10\n\t"                                      \
          "v_bcnt_u32_b32 %2, %0, %2\n\t"                                   \
          "v_bcnt_u32_b32 %3, %1, %3\n\t"                                   \
          "v_xor_b32 %0, %15, %7\n\t"                                       \
          "v_xor_b32 %1, %15, %11\n\t"                                      \
          "v_bcnt_u32_b32 %2, %0, %2\n\t"                                   \
          "v_bcnt_u32_b32 %3, %1, %3"                                       \
          : "=&v"(t0_), "=&v"(t1_), "+v"(accA), "+v"(accB)                  \
          : "v"((xa).x), "v"((xa).y), "v"((xa).z), "v"((xa).w),             \
            "v"((xb).x), "v"((xb).y), "v"((xb).z), "v"((xb).w),             \
            "s"((wv).x), "s"((wv).y), "s"((wv).z), "s"((wv).w)); }

// ---------------------------------------------------------------------------
// Binary GEMM layer. 128 rows x 128 cols per 256-thread block, 1024 blocks
// (4 blocks/CU -> 4 waves/SIMD; R8's 512-block grid starved TLP).
// Thread = rows {lane, lane+64}; wave = 32 cols (wave-uniform).
// X in LDS, pitch 16 u64, XOR-swizzled at uint4 granularity:
//   slot' = slot ^ (row & 7); rows lane/lane+64 share constant (lane & 7).
// W + thresholds via wave-uniform scalar loads; MAC pinned via MACQ2.
__global__ void __launch_bounds__(256)
gemm_bin_kernel(const u64* __restrict__ Xin, const u64* __restrict__ Wp,
                const int2* __restrict__ th, u64* __restrict__ Xout) {
    __shared__ u64 Xs[128][KW];      // 16 KB, swizzled storage

    const int tid = threadIdx.x;
    const int bc = blockIdx.x & 7;    // col block (8 x 128 cols)
    const int br = blockIdx.x >> 3;   // row block (128 x 128 rows)
    const int r0 = br * 128;

    // stage X: 2048 u64; for fixed k, consecutive tids hit consecutive rows
#pragma unroll
    for (int k = 0; k < 8; ++k) {
        int f = tid + k * 256;
        int row = f & 127;
        int wq = f >> 7;
        int slot = (((wq >> 1) ^ (row & 7)) << 1) | (wq & 1);
        Xs[row][slot] = Xin[(size_t)wq * BATCH + r0 + row];
    }
    __syncthreads();

    const int lane = tid & 63;
    const int w = __builtin_amdgcn_readfirstlane(tid >> 6);   // wave id, SGPR
    const int cbase = bc * 128 + w * 32;                      // scalar
    const int c = lane & 7;                                   // swizzle const

    const uint4* xr0 = (const uint4*)&Xs[lane][0];
    const uint4* xr1 = (const uint4*)&Xs[lane + 64][0];

    unsigned int bits0 = 0, bits1 = 0;

#pragma unroll 1
    for (int jc = 0; jc < 4; ++jc) {
        int acc0[8], acc1[8];
#pragma unroll
        for (int u = 0; u < 8; ++u) { acc0[u] = 0; acc1[u] = 0; }

#pragma unroll
        for (int sp = 0; sp < 8; ++sp) {          // uint4 slots (2 u64 each)
            uint4 xa = xr0[sp ^ c];
            uint4 xb = xr1[sp ^ c];
#pragma unroll
            for (int u = 0; u < 8; ++u) {
                const uint4* wrow = (const uint4*)(Wp + (size_t)(cbase + jc * 8 + u) * KW);
                uint4 wv = wrow[sp];               // scalar load (uniform addr)
                MACQ2(acc0[u], acc1[u], xa, xb, wv);
            }
        }
#pragma unroll
        for (int u = 0; u < 8; ++u) {
            int2 t = th[cbase + jc * 8 + u];
            int h0 = 1024 - 2 * acc0[u];
            int h1 = 1024 - 2 * acc1[u];
            unsigned int s = (unsigned int)(jc * 8 + u);
            bits0 |= (unsigned int)(t.y ? (h0 <= t.x) : (h0 >= t.x)) << s;
            bits1 |= (unsigned int)(t.y ? (h1 <= t.x) : (h1 >= t.x)) << s;
        }
    }

    // store: output strips as u32 halves; wq = cbase>>6, half = (cbase>>5)&1
    const int wq = cbase >> 6;
    const int half = (cbase >> 5) & 1;
    unsigned int* out32 = (unsigned int*)Xout;
    size_t ob = (size_t)wq * 2 * BATCH;
    out32[ob + (r0 + lane) * 2 + half]      = bits0;
    out32[ob + (r0 + lane + 64) * 2 + half] = bits1;
}

// ---------------------------------------------------------------------------
// Final 1024 -> 10 binary matmul + TensorNorm. X3 column-major strips.
__global__ void __launch_bounds__(256) final_layer_kernel(
    const u64* __restrict__ X3, const u64* __restrict__ W4p,
    const float* __restrict__ tw, const float* __restrict__ tb,
    const float* __restrict__ tm, const float* __restrict__ tv,
    float* __restrict__ out) {
    __shared__ u64 Wl[NCLS * KW];
    if (threadIdx.x < NCLS * KW) Wl[threadIdx.x] = W4p[threadIdx.x];
    __syncthreads();

    int row = blockIdx.x * 256 + threadIdx.x;
    u64 xr[KW];
#pragma unroll
    for (int wq = 0; wq < KW; ++wq) xr[wq] = X3[(size_t)wq * BATCH + row];

    double sc = (double)tw[0] / sqrt((double)tv[0] + 1e-4);
    double off = (double)tb[0] - (double)tm[0] * sc;

#pragma unroll
    for (int cc = 0; cc < NCLS; ++cc) {
        int p = 0;
#pragma unroll
        for (int wq = 0; wq < KW; ++wq)
            p += __builtin_popcountll(xr[wq] ^ Wl[cc * KW + wq]);
        int h = 1024 - 2 * p;
        out[(size_t)row * NCLS + cc] = (float)((double)h * sc + off);
    }
}

// ---------------------------------------------------------------------------
extern "C" void kernel_launch(void* const* d_in, const int* in_sizes, int n_in,
                              void* d_out, int out_size, void* d_ws, size_t ws_size,
                              hipStream_t stream) {
    const float* x  = (const float*)d_in[0];
    const float* W1 = (const float*)d_in[1];
    const float* W2 = (const float*)d_in[2];
    const float* W3 = (const float*)d_in[3];
    const float* W4 = (const float*)d_in[4];
    const float* g1 = (const float*)d_in[5];
    const float* b1 = (const float*)d_in[6];
    const float* m1 = (const float*)d_in[7];
    const float* v1 = (const float*)d_in[8];
    const float* g2 = (const float*)d_in[9];
    const float* b2 = (const float*)d_in[10];
    const float* m2 = (const float*)d_in[11];
    const float* v2 = (const float*)d_in[12];
    const float* g3 = (const float*)d_in[13];
    const float* b3 = (const float*)d_in[14];
    const float* m3 = (const float*)d_in[15];
    const float* v3 = (const float*)d_in[16];
    const float* tw = (const float*)d_in[17];
    const float* tb = (const float*)d_in[18];
    const float* tm = (const float*)d_in[19];
    const float* tv = (const float*)d_in[20];

    char* ws = (char*)d_ws;
    u64* XA  = (u64*)(ws + OFF_XA);
    u64* XB  = (u64*)(ws + OFF_XB);
    u64* Wp1 = (u64*)(ws + OFF_WP1);
    u64* Wp2 = (u64*)(ws + OFF_WP2);
    u64* Wp3 = (u64*)(ws + OFF_WP3);
    u64* Wp4 = (u64*)(ws + OFF_WP4);
    int2* TH = (int2*)(ws + OFF_TH);

    prep_kernel<<<NB_PACK + NB_TH, 256, 0, stream>>>(x, W1, W2, W3, W4,
                                                     g1, b1, m1, v1,
                                                     g2, b2, m2, v2,
                                                     g3, b3, m3, v3,
                                                     XA, Wp1, Wp2, Wp3, Wp4, TH);

    gemm_bin_kernel<<<1024, 256, 0, stream>>>(XA, Wp1, TH,        XB);
    gemm_bin_kernel<<<1024, 256, 0, stream>>>(XB, Wp2, TH + 1024, XA);
    gemm_bin_kernel<<<1024, 256, 0, stream>>>(XA, Wp3, TH + 2048, XB);

    final_layer_kernel<<<64, 256, 0, stream>>>(XB, Wp4, tw, tb, tm, tv,
                                               (float*)d_out);
}